// Round 15
// baseline (2541.143 us; speedup 1.0000x reference)
//
#include <hip/hip_runtime.h>

#define LL 8
#define DD 1024
#define VV 32000
#define SS 2048
#define BB 2
#define NROWS 4096          // B*S
#define DT_STEP 0.055f      // 0.5*(dt_min+dt_max)
#define HALF_DT 0.0275f
#define TUNNEL_SCALE 1.55f  // 1 + dt/dt_max

typedef __attribute__((ext_vector_type(8))) short bf16x8;
typedef __attribute__((ext_vector_type(4))) float f32x4;

static __device__ __forceinline__ float bf2f(unsigned short u){
  union { unsigned int i; float f; } v; v.i = ((unsigned int)u) << 16; return v.f;
}
static __device__ __forceinline__ unsigned short f2bf(float f){
  union { float f; unsigned int i; } v; v.f = f;
  unsigned int r = v.i + 0x7fffu + ((v.i >> 16) & 1u);
  return (unsigned short)(r >> 16);
}

// async global->LDS, 16B per lane. lds dest must be wave-uniform base; HW adds lane*16.
static __device__ __forceinline__ void gl16(const unsigned short* g, unsigned short* l){
  __builtin_amdgcn_global_load_lds(
      (const __attribute__((address_space(1))) unsigned int*)g,
      (__attribute__((address_space(3))) unsigned int*)l, 16, 0, 0);
}

__device__ __forceinline__ float block_sum256(float v, volatile float* scratch){
  #pragma unroll
  for (int off = 32; off; off >>= 1) v += __shfl_down(v, off, 64);
  int w = threadIdx.x >> 6, lane = threadIdx.x & 63;
  __syncthreads();
  if (lane == 0) scratch[w] = v;
  __syncthreads();
  return scratch[0] + scratch[1] + scratch[2] + scratch[3];
}

// ---------------- encode: phase embedding -> f32 master + bf16 hi/lo ----------------
__global__ void encode_kernel(const int* __restrict__ ids, float* __restrict__ s_f32,
                              unsigned short* __restrict__ hi, unsigned short* __restrict__ lo){
  int row = blockIdx.x;            // 0..4095 = b*S+s
  int t = threadIdx.x;
  float theta = 6.28318530717958647692f * (float)ids[row] / 32000.0f;
  #pragma unroll
  for (int i = 0; i < 2; ++i){
    int kk = t + i * 256;          // 0..511
    float ang = theta * (float)(kk + 1);
    float sv, cv; sincosf(ang, &sv, &cv);
    float c = cv * 0.03125f, s = sv * 0.03125f;   // 1/sqrt(D)
    long b0 = (long)row * DD + kk, b1 = b0 + 512;
    s_f32[b0] = c; s_f32[b1] = s;
    unsigned short ch = f2bf(c); hi[b0] = ch; lo[b0] = f2bf(c - bf2f(ch));
    unsigned short sh = f2bf(s); hi[b1] = sh; lo[b1] = f2bf(s - bf2f(sh));
  }
}

// ---------------- bf16 tiled transpose (hi+lo pair): [b][R][C] -> [b][C][R] ----------
__global__ void transpose_bf16_pair_kernel(const unsigned short* __restrict__ in_hi,
                                           const unsigned short* __restrict__ in_lo,
                                           unsigned short* __restrict__ out_hi,
                                           unsigned short* __restrict__ out_lo,
                                           int R, int C){
  __shared__ __align__(16) unsigned short tile[64][80];
  int zz = blockIdx.z;                       // (batch<<1) | sel
  const unsigned short* in = (zz & 1) ? in_lo : in_hi;
  unsigned short* out = (zz & 1) ? out_lo : out_hi;
  long ib = (long)(zz >> 1) * R * C;
  int c0 = blockIdx.x * 64, r0 = blockIdx.y * 64;
  int t = threadIdx.x;
  #pragma unroll
  for (int i = 0; i < 2; ++i){
    int j = t + i * 256; int row = j >> 3, cc = j & 7;
    *(uint4*)&tile[row][cc * 8] = *(const uint4*)(in + ib + (long)(r0 + row) * C + c0 + cc * 8);
  }
  __syncthreads();
  #pragma unroll
  for (int i = 0; i < 2; ++i){
    int j = t + i * 256; int orow = j >> 3, cc = j & 7;
    union { unsigned short u[8]; uint4 v; } tmp;
    #pragma unroll
    for (int e = 0; e < 8; ++e) tmp.u[e] = tile[cc * 8 + e][orow];
    *(uint4*)(out + ib + (long)(c0 + orow) * R + r0 + cc * 8) = tmp.v;
  }
}

// -------- f32 -> bf16 (optionally hi/lo split) transposing convert --------------------
template<bool SPLIT>
__global__ void transpose_f32_bf16_kernel(const float* __restrict__ in,
                                          unsigned short* __restrict__ ohi,
                                          unsigned short* __restrict__ olo, int R, int C){
  __shared__ float tile[64][68];
  long ib = (long)blockIdx.z * R * C;
  int c0 = blockIdx.x * 64, r0 = blockIdx.y * 64;
  int t = threadIdx.x;
  #pragma unroll
  for (int i = 0; i < 4; ++i){
    int j = t + i * 256; int row = j >> 4, cc = j & 15;
    *(float4*)&tile[row][cc * 4] = *(const float4*)(in + ib + (long)(r0 + row) * C + c0 + cc * 4);
  }
  __syncthreads();
  #pragma unroll
  for (int i = 0; i < 2; ++i){
    int j = t + i * 256; int orow = j >> 3, cc = j & 7;
    union { unsigned short u[8]; uint4 v; } th, tl;
    #pragma unroll
    for (int e = 0; e < 8; ++e){
      float v = tile[cc * 8 + e][orow];
      unsigned short h = f2bf(v); th.u[e] = h;
      if (SPLIT) tl.u[e] = f2bf(v - bf2f(h));
    }
    long ob = ib + (long)(c0 + orow) * R + r0 + cc * 8;
    *(uint4*)(ohi + ob) = th.v;
    if (SPLIT) *(uint4*)(olo + ob) = tl.v;
  }
}

// ---------------- split NT GEMM (128x128, 8 waves, dbuf, 2-phase): C = alpha*A@B^T ----
// r11-proven 2-phase fine interleave. Operands (hi,lo) bf16 pairs -> 3 MFMA products.
// LDS [2 dbuf][128 rows][64]: row = K-32 slab, chunks 0-3 hi / 4-7 lo, slot = chunk^(row&7).
// OUTMODE: 0 = f32 C (+bias); 2 = bf16 hi/lo (score); 5 = plain f32 to (ks? C2 : C)
// CAUSAL: 0 none; 1 score-mode (skip upper, mask diag); 2 pv k-limit;
//         3 = SPLIT-K pv: grid 192/batch = {ks=0: mt 0..15 x nt 0..7 over k[0,1024)} +
//             {ks=1: mt 8..15 x nt 0..7 over k[1024,Keff)}; ks=1 writes C2 (via Chi).
//         4 = SPLIT-K uniform: grid 2*MT*NT; ks over K halves; ks=1 writes C2.
template<int OUTMODE, int CAUSAL>
__global__ __launch_bounds__(512, 4)
void gemm_nt_kernel(const unsigned short* __restrict__ Ahi, const unsigned short* __restrict__ Alo,
                    const unsigned short* __restrict__ Bhi, const unsigned short* __restrict__ Blo,
                    float* __restrict__ C, unsigned short* __restrict__ Chi,
                    unsigned short* __restrict__ Clo, const float* __restrict__ bias,
                    int K, int lda, int ldb, int ldc, int MT, int NT,
                    long batchA, long batchB, long batchC, float alpha)
{
  const int bz = blockIdx.y;
  int mt, nt, ks = 0;
  {
    const int nwg = (CAUSAL == 4) ? (MT * NT * 2) : (MT * NT);
    const int q = nwg >> 3, r = nwg & 7;
    const int xcd = blockIdx.x & 7, off = blockIdx.x >> 3;
    const int wg = (xcd < r ? xcd * (q + 1) : r * (q + 1) + (xcd - r) * q) + off;
    if (CAUSAL == 3){
      if (wg < 128){ ks = 0; mt = wg >> 3; nt = wg & 7; }
      else { int w2 = wg - 128; ks = 1; mt = 8 + (w2 >> 3); nt = w2 & 7; }
    } else if (CAUSAL == 4){
      int w2 = wg; ks = 0;
      if (w2 >= MT * NT){ ks = 1; w2 -= MT * NT; }
      mt = w2 / NT; nt = w2 - mt * NT;
    } else {
      const int band = wg / (NT << 3), rem = wg - band * (NT << 3);
      mt = (band << 3) + (rem & 7); nt = rem >> 3;
    }
  }
  if (CAUSAL == 1 && nt > mt) return;
  const int m0 = mt << 7, n0 = nt << 7;
  int kstart = 0, kend = K;
  if (CAUSAL == 2){ int kl = (mt + 1) << 7; kend = kl < K ? kl : K; }
  if (CAUSAL == 3){
    kstart = ks << 10;
    int kl = (mt + 1) << 7, kc = kstart + 1024;
    kend = kl < kc ? kl : kc;
  }
  if (CAUSAL == 4){
    kstart = ks * (K >> 1);
    kend = kstart + (K >> 1);
  }

  __shared__ __align__(16) unsigned short sA[2][128][64];
  __shared__ __align__(16) unsigned short sB[2][128][64];

  const int tid = threadIdx.x;
  const int lane = tid & 63;
  const int w = tid >> 6;              // 0..7
  const int wr = w >> 2, wc = w & 3;   // 2 x 4 wave grid, 64x32 per wave
  const int fr = lane & 15, fc = lane >> 4;
  const int fr7 = fr & 7;

  f32x4 acc[4][2];
  #pragma unroll
  for (int i = 0; i < 4; ++i)
    #pragma unroll
    for (int j = 0; j < 2; ++j) acc[i][j] = (f32x4){0.f, 0.f, 0.f, 0.f};

  const int srow = tid >> 3, slot = tid & 7;
  const int cont = slot ^ (srow & 7);         // content chunk at this slot
  const long aoff = (long)bz * batchA, boff = (long)bz * batchB;
  const int gcol = (cont & 3) << 3;
  const unsigned short* gA = (cont >= 4 ? Alo : Ahi) + aoff + (long)(m0 + srow) * lda + gcol;
  const unsigned short* gB = (cont >= 4 ? Blo : Bhi) + boff + (long)(n0 + srow) * ldb + gcol;
  const long rstepA = 64L * lda, rstepB = 64L * ldb;
  const int wofs = w << 9;                    // wave base: w*8 rows * 64 elems

  const int oh = (fc ^ fr7) << 4;
  const int ol = ((4 + fc) ^ fr7) << 4;

  const int ntiles = (kend - kstart) >> 5;

  // prologue: stage tile 0 fully (A0,A1,B0,B1 in that order)
  gl16(gA + kstart,          &sA[0][0][0] + wofs);
  gl16(gA + kstart + rstepA, &sA[0][0][0] + 4096 + wofs);
  gl16(gB + kstart,          &sB[0][0][0] + wofs);
  gl16(gB + kstart + rstepB, &sB[0][0][0] + 4096 + wofs);

  int cur = 0;
  for (int t = 0; t < ntiles; ++t){
    const bool stg = (t < ntiles - 1);
    const long nk = kstart + ((long)(t + 1) << 5);
    const char* bA_ = (const char*)&sA[cur][0][0];
    const char* bB_ = (const char*)&sB[cur][0][0];
    bf16x8 ah_[4], al_[4];

    // ---- phase 0: stage A of t+1; certify tile t; read A-frags + B ni=0; 12 MFMA ----
    if (stg){
      gl16(gA + nk,          &sA[cur ^ 1][0][0] + wofs);
      gl16(gA + nk + rstepA, &sA[cur ^ 1][0][0] + 4096 + wofs);
      asm volatile("s_waitcnt vmcnt(2)" ::: "memory");   // tile-t's 4 loads landed
    } else {
      asm volatile("s_waitcnt vmcnt(0)" ::: "memory");
    }
    asm volatile("s_barrier" ::: "memory");              // cross-wave certify
    #pragma unroll
    for (int mi = 0; mi < 4; ++mi){
      const char* p_ = bA_ + (wr * 64 + mi * 16 + fr) * 128;
      ah_[mi] = *(const bf16x8*)(p_ + oh);
      al_[mi] = *(const bf16x8*)(p_ + ol);
    }
    {
      const char* pb_ = bB_ + (wc * 32 + fr) * 128;
      bf16x8 bh_ = *(const bf16x8*)(pb_ + oh);
      bf16x8 bl_ = *(const bf16x8*)(pb_ + ol);
      __builtin_amdgcn_s_setprio(1);
      #pragma unroll
      for (int mi = 0; mi < 4; ++mi){
        acc[mi][0] = __builtin_amdgcn_mfma_f32_16x16x32_bf16(ah_[mi], bh_, acc[mi][0], 0, 0, 0);
        acc[mi][0] = __builtin_amdgcn_mfma_f32_16x16x32_bf16(ah_[mi], bl_, acc[mi][0], 0, 0, 0);
        acc[mi][0] = __builtin_amdgcn_mfma_f32_16x16x32_bf16(al_[mi], bh_, acc[mi][0], 0, 0, 0);
      }
      __builtin_amdgcn_s_setprio(0);
    }

    // ---- phase 1: stage B of t+1; barrier; read B ni=1; 12 MFMA ----------------------
    if (stg){
      gl16(gB + nk,          &sB[cur ^ 1][0][0] + wofs);
      gl16(gB + nk + rstepB, &sB[cur ^ 1][0][0] + 4096 + wofs);
    }
    asm volatile("s_barrier" ::: "memory");
    {
      const char* pb_ = bB_ + (wc * 32 + 16 + fr) * 128;
      bf16x8 bh_ = *(const bf16x8*)(pb_ + oh);
      bf16x8 bl_ = *(const bf16x8*)(pb_ + ol);
      __builtin_amdgcn_s_setprio(1);
      #pragma unroll
      for (int mi = 0; mi < 4; ++mi){
        acc[mi][1] = __builtin_amdgcn_mfma_f32_16x16x32_bf16(ah_[mi], bh_, acc[mi][1], 0, 0, 0);
        acc[mi][1] = __builtin_amdgcn_mfma_f32_16x16x32_bf16(ah_[mi], bl_, acc[mi][1], 0, 0, 0);
        acc[mi][1] = __builtin_amdgcn_mfma_f32_16x16x32_bf16(al_[mi], bh_, acc[mi][1], 0, 0, 0);
      }
      __builtin_amdgcn_s_setprio(0);
    }
    cur ^= 1;
  }

  const long coff = (long)bz * batchC;
  float* Cout = ((OUTMODE == 5 || CAUSAL == 4) && ks) ? (float*)Chi : C;
  const int rb0 = m0 + wr * 64 + fc * 4;   // + mi*16 + rg
  const int cb0 = n0 + wc * 32 + fr;       // + ni*16
  #pragma unroll
  for (int mi = 0; mi < 4; ++mi){
    #pragma unroll
    for (int ni = 0; ni < 2; ++ni){
      #pragma unroll
      for (int rg = 0; rg < 4; ++rg){
        int row = rb0 + mi * 16 + rg;
        int col = cb0 + ni * 16;
        float v = acc[mi][ni][rg] * alpha;
        long idx = coff + (long)row * ldc + col;
        if (OUTMODE == 0){
          if (bias && ks == 0) v += bias[col];   // bias only in the ks=0 partial
          Cout[idx] = v;
        } else if (OUTMODE == 2){
          if (CAUSAL == 1 && col > row) v = 0.0f;   // causal mask (k > q)
          unsigned short h = f2bf(v);
          Chi[idx] = h;
          Clo[idx] = f2bf(v - bf2f(h));
        } else {                                    // OUTMODE 5: plain partial store
          Cout[idx] = v;
        }
      }
    }
  }
}

// ---------------- 128x128 vocab GEMM, 2 blocks/CU: C = A @ B^T + LSE partials ---------
// r13-proven: 64 KB LDS -> 2 co-resident blocks hide vmcnt/barrier stalls.
// r11 2-phase schedule, plain bf16. Wave grid 4x2 -> 500 LSE slots/row.
__global__ __launch_bounds__(512, 4)
void gemm256_kernel(const unsigned short* __restrict__ A,    // [4096][1024] bf16
                    const unsigned short* __restrict__ Bt,   // [32000][1024] bf16
                    float* __restrict__ C,                   // [4096][32000] f32
                    float* __restrict__ psum)                // [4096][512] (500 used)
{
  const int MT = 32, NT = 250;
  const int nwg = MT * NT;                 // 8000
  const int q = nwg >> 3;                  // 1000, r = 0
  const int xcd = blockIdx.x & 7, off = blockIdx.x >> 3;
  const int wg = xcd * q + off;
  const int band = wg / (NT << 3), rem = wg - band * (NT << 3);
  const int mt = (band << 3) + (rem & 7), nt = rem >> 3;
  const int m0 = mt << 7, n0 = nt << 7;

  __shared__ __align__(16) unsigned short sA[2][128][64];   // 32 KB
  __shared__ __align__(16) unsigned short sB[2][128][64];   // 32 KB

  const int tid = threadIdx.x;
  const int lane = tid & 63;
  const int w = tid >> 6;
  const int wr = w >> 1, wc = w & 1;       // 4 x 2 wave grid, 32x64 per wave
  const int fr = lane & 15, fc = lane >> 4;
  const int fr7 = fr & 7;

  f32x4 acc[2][4];
  #pragma unroll
  for (int i = 0; i < 2; ++i)
    #pragma unroll
    for (int j = 0; j < 4; ++j) acc[i][j] = (f32x4){0.f, 0.f, 0.f, 0.f};

  const int srow = tid >> 3, slot = tid & 7;   // srow 0..63
  const int cont = slot ^ (srow & 7);
  const unsigned short* gA = A  + (long)(m0 + srow) * DD + (cont << 3);
  const unsigned short* gB = Bt + (long)(n0 + srow) * DD + (cont << 3);
  const long rstep = 64L * DD;
  const int wofs = w << 9;                 // w*8 rows * 64 elems

  const int oh = (fc ^ fr7) << 4;          // ks=0 chunk
  const int ol = ((4 + fc) ^ fr7) << 4;    // ks=1 chunk

  // prologue: stage tile 0 fully (A0,A1,B0,B1)
  gl16(gA,         &sA[0][0][0] + wofs);
  gl16(gA + rstep, &sA[0][0][0] + 4096 + wofs);
  gl16(gB,         &sB[0][0][0] + wofs);
  gl16(gB + rstep, &sB[0][0][0] + 4096 + wofs);

  int cur = 0;
  for (int t = 0; t < 16; ++t){
    const bool stg = (t < 15);
    const long nk = (long)(t + 1) << 6;    // BK=64
    const char* bA_ = (const char*)&sA[cur][0][0];
    const char* bB_ = (const char*)&sB[cur][0][0];
    bf16x8 aq[2][2], bq[4][2];

    // ---- phase 0: stage A of t+1; certify tile t; read A + B ni=0,1; 8 MFMA ----
    if (stg){
      gl16(gA + nk,         &sA[cur ^ 1][0][0] + wofs);
      gl16(gA + nk + rstep, &sA[cur ^ 1][0][0] + 4096 + wofs);
      asm volatile("s_waitcnt vmcnt(2)" ::: "memory");
    } else {
      asm volatile("s_waitcnt vmcnt(0)" ::: "memory");
    }
    asm volatile("s_barrier" ::: "memory");
    #pragma unroll
    for (int mi = 0; mi < 2; ++mi){
      const char* p = bA_ + (wr * 32 + mi * 16 + fr) * 128;
      aq[mi][0] = *(const bf16x8*)(p + oh);
      aq[mi][1] = *(const bf16x8*)(p + ol);
    }
    #pragma unroll
    for (int ni = 0; ni < 2; ++ni){
      const char* p = bB_ + (wc * 64 + ni * 16 + fr) * 128;
      bq[ni][0] = *(const bf16x8*)(p + oh);
      bq[ni][1] = *(const bf16x8*)(p + ol);
    }
    __builtin_amdgcn_s_setprio(1);
    #pragma unroll
    for (int ks = 0; ks < 2; ++ks)
      #pragma unroll
      for (int mi = 0; mi < 2; ++mi)
        #pragma unroll
        for (int ni = 0; ni < 2; ++ni)
          acc[mi][ni] = __builtin_amdgcn_mfma_f32_16x16x32_bf16(aq[mi][ks], bq[ni][ks], acc[mi][ni], 0, 0, 0);
    __builtin_amdgcn_s_setprio(0);

    // ---- phase 1: stage B of t+1; barrier; read B ni=2,3; 8 MFMA ----
    if (stg){
      gl16(gB + nk,         &sB[cur ^ 1][0][0] + wofs);
      gl16(gB + nk + rstep, &sB[cur ^ 1][0][0] + 4096 + wofs);
    }
    asm volatile("s_barrier" ::: "memory");
    #pragma unroll
    for (int ni = 2; ni < 4; ++ni){
      const char* p = bB_ + (wc * 64 + ni * 16 + fr) * 128;
      bq[ni][0] = *(const bf16x8*)(p + oh);
      bq[ni][1] = *(const bf16x8*)(p + ol);
    }
    __builtin_amdgcn_s_setprio(1);
    #pragma unroll
    for (int ks = 0; ks < 2; ++ks)
      #pragma unroll
      for (int mi = 0; mi < 2; ++mi)
        #pragma unroll
        for (int ni = 2; ni < 4; ++ni)
          acc[mi][ni] = __builtin_amdgcn_mfma_f32_16x16x32_bf16(aq[mi][ks], bq[ni][ks], acc[mi][ni], 0, 0, 0);
    __builtin_amdgcn_s_setprio(0);

    cur ^= 1;
  }

  const int rb0 = m0 + wr * 32 + fc * 4;
  const int cb0 = n0 + wc * 64 + fr;
  #pragma unroll
  for (int mi = 0; mi < 2; ++mi){
    #pragma unroll
    for (int ni = 0; ni < 4; ++ni){
      #pragma unroll
      for (int rg = 0; rg < 4; ++rg){
        C[(long)(rb0 + mi * 16 + rg) * VV + cb0 + ni * 16] = acc[mi][ni][rg];
      }
    }
  }

  // max-free sum-exp partials: |logit| <= ~0.7, exp cannot overflow.
  // slot = nt*2 + wc (nt 0..249, wc 0..1) -> 500 slots/row, 64 cols each.
  #pragma unroll
  for (int mi = 0; mi < 2; ++mi){
    #pragma unroll
    for (int rg = 0; rg < 4; ++rg){
      float s4 = __expf(acc[mi][0][rg]) + __expf(acc[mi][1][rg])
               + __expf(acc[mi][2][rg]) + __expf(acc[mi][3][rg]);
      #pragma unroll
      for (int o = 1; o < 16; o <<= 1) s4 += __shfl_xor(s4, o, 64);
      if (fr == 0){
        long pidx = ((long)(rb0 + mi * 16 + rg) << 9) + nt * 2 + wc;
        psum[pidx] = s4;
      }
    }
  }
}

// ---------------- combiners / elementwise --------------------------------------------
// mid_trans: k1 = k1a + (row>=1024? k1b); mid = s + dt*k1 -> op hi/lo AND T hi/lo
__global__ void mid_trans_kernel(const float* __restrict__ s, float* __restrict__ k1,
                                 const float* __restrict__ k1b,
                                 unsigned short* __restrict__ ohi, unsigned short* __restrict__ olo,
                                 unsigned short* __restrict__ thi, unsigned short* __restrict__ tlo){
  __shared__ float tile[64][68];
  int c0 = blockIdx.x * 64, r0g = blockIdx.y * 64;   // r0g in [0,4096), tiles don't cross batch
  int t = threadIdx.x;
  #pragma unroll
  for (int i = 0; i < 4; ++i){
    int j = t + i * 256; int row = j >> 4, cc = (j & 15) * 4;
    long idx = (long)(r0g + row) * DD + c0 + cc;
    float4 a = *(const float4*)(k1 + idx);
    if (((r0g + row) & 2047) >= 1024){
      float4 b = *(const float4*)(k1b + idx);
      a.x += b.x; a.y += b.y; a.z += b.z; a.w += b.w;
    }
    *(float4*)(k1 + idx) = a;
    float4 sv = *(const float4*)(s + idx);
    float4 m;
    m.x = sv.x + DT_STEP * a.x; m.y = sv.y + DT_STEP * a.y;
    m.z = sv.z + DT_STEP * a.z; m.w = sv.w + DT_STEP * a.w;
    *(float4*)&tile[row][cc] = m;
    ushort4 hv, lv;
    hv.x = f2bf(m.x); lv.x = f2bf(m.x - bf2f(hv.x));
    hv.y = f2bf(m.y); lv.y = f2bf(m.y - bf2f(hv.y));
    hv.z = f2bf(m.z); lv.z = f2bf(m.z - bf2f(hv.z));
    hv.w = f2bf(m.w); lv.w = f2bf(m.w - bf2f(hv.w));
    *(ushort4*)(ohi + idx) = hv; *(ushort4*)(olo + idx) = lv;
  }
  __syncthreads();
  long tb = (long)(r0g >> 11) * DD * SS;
  int sb = r0g & 2047;
  #pragma unroll
  for (int i = 0; i < 2; ++i){
    int j = t + i * 256; int ocol = j >> 3, cc = (j & 7) * 8;
    union { unsigned short u[8]; uint4 v; } th, tl;
    #pragma unroll
    for (int e = 0; e < 8; ++e){
      float v = tile[cc + e][ocol];
      unsigned short h = f2bf(v);
      th.u[e] = h; tl.u[e] = f2bf(v - bf2f(h));
    }
    long ob = tb + (long)(c0 + ocol) * SS + sb + cc;
    *(uint4*)(thi + ob) = th.v;
    *(uint4*)(tlo + ob) = tl.v;
  }
}

// ev_energy: ev = s + 0.5dt*(k1 + k2a + (row>=1024? k2b)); in-place over k2; row energy
__global__ void ev_energy_kernel(const float* __restrict__ s, const float* __restrict__ k1,
                                 float* __restrict__ k2, const float* __restrict__ k2b,
                                 float* __restrict__ energy){
  int row = blockIdx.x, t = threadIdx.x;
  long base = (long)row * DD + t * 4;
  float4 sv = *(const float4*)(s + base);
  float4 av = *(const float4*)(k1 + base);
  float4 bv = *(const float4*)(k2 + base);
  if ((row & 2047) >= 1024){
    float4 cv = *(const float4*)(k2b + base);
    bv.x += cv.x; bv.y += cv.y; bv.z += cv.z; bv.w += cv.w;
  }
  float4 ev;
  ev.x = sv.x + HALF_DT * (av.x + bv.x);
  ev.y = sv.y + HALF_DT * (av.y + bv.y);
  ev.z = sv.z + HALF_DT * (av.z + bv.z);
  ev.w = sv.w + HALF_DT * (av.w + bv.w);
  *(float4*)(k2 + base) = ev;
  __shared__ float scratch[4];
  float n2 = block_sum256(ev.x*ev.x + ev.y*ev.y + ev.z*ev.z + ev.w*ev.w, scratch);
  if (t == 0) energy[row] = sqrtf(n2);
}

// tunnel with FUSED batch-mean: each block redundantly reduces its batch's 2048
// energies (8 KB, L2-resident; same strided-load + tree as the old mean_energy ->
// bit-identical thr). Removes the 2-block mean_energy serialization bubble.
__global__ void tunnel_kernel(const float* __restrict__ ev, const float* __restrict__ energy,
                              unsigned short* __restrict__ hi, unsigned short* __restrict__ lo){
  int row = blockIdx.x, t = threadIdx.x;
  const float* eb = energy + (row >> 11) * SS;
  float s = 0.f;
  for (int j = t; j < SS; j += 256) s += eb[j];
  __shared__ float scratch[4];
  float thr = block_sum256(s, scratch) * (1.0f / SS);
  float scale = (energy[row] < thr) ? TUNNEL_SCALE : 1.0f;
  long base = (long)row * DD + t * 4;
  float4 v = *(const float4*)(ev + base);
  v.x *= scale; v.y *= scale; v.z *= scale; v.w *= scale;
  ushort4 hv, lv;
  hv.x = f2bf(v.x); lv.x = f2bf(v.x - bf2f(hv.x));
  hv.y = f2bf(v.y); lv.y = f2bf(v.y - bf2f(hv.y));
  hv.z = f2bf(v.z); lv.z = f2bf(v.z - bf2f(hv.z));
  hv.w = f2bf(v.w); lv.w = f2bf(v.w - bf2f(hv.w));
  *(ushort4*)(hi + base) = hv; *(ushort4*)(lo + base) = lv;
}

// ln: h = ha + hb (proj split-K combine), then LayerNorm -> s_f32 + op hi/lo
__global__ void ln_kernel(const float* __restrict__ h, const float* __restrict__ hb,
                          const float* __restrict__ w,
                          const float* __restrict__ b, float* __restrict__ s_f32,
                          unsigned short* __restrict__ hi, unsigned short* __restrict__ lo){
  int row = blockIdx.x, t = threadIdx.x;
  long base = (long)row * DD + t * 4;
  float4 xv = *(const float4*)(h + base);
  float4 xb = *(const float4*)(hb + base);
  xv.x += xb.x; xv.y += xb.y; xv.z += xb.z; xv.w += xb.w;
  __shared__ float scratch[4];
  float sum = block_sum256(xv.x + xv.y + xv.z + xv.w, scratch);
  float ssq = block_sum256(xv.x*xv.x + xv.y*xv.y + xv.z*xv.z + xv.w*xv.w, scratch);
  float mu = sum * (1.0f / DD);
  float var = ssq * (1.0f / DD) - mu * mu;
  float rstd = rsqrtf(var + 1e-5f);
  float4 wv = *(const float4*)(w + t * 4), bv = *(const float4*)(b + t * 4);
  float y0 = (xv.x - mu) * rstd * wv.x + bv.x;
  float y1 = (xv.y - mu) * rstd * wv.y + bv.y;
  float y2 = (xv.z - mu) * rstd * wv.z + bv.z;
  float y3 = (xv.w - mu) * rstd * wv.w + bv.w;
  float4 o; o.x = y0; o.y = y1; o.z = y2; o.w = y3;
  *(float4*)(s_f32 + base) = o;
  ushort4 hv, lv;
  hv.x = f2bf(y0); lv.x = f2bf(y0 - bf2f(hv.x));
  hv.y = f2bf(y1); lv.y = f2bf(y1 - bf2f(hv.y));
  hv.z = f2bf(y2); lv.z = f2bf(y2 - bf2f(hv.z));
  hv.w = f2bf(y3); lv.w = f2bf(y3 - bf2f(hv.w));
  *(ushort4*)(hi + base) = hv; *(ushort4*)(lo + base) = lv;
}

// final LN + unit-normalize -> bf16 (plain; un-amplified error)
__global__ void fln_kernel(const float* __restrict__ s, const float* __restrict__ w,
                           const float* __restrict__ b, unsigned short* __restrict__ uhi){
  int row = blockIdx.x, t = threadIdx.x;
  long base = (long)row * DD + t * 4;
  float4 xv = *(const float4*)(s + base);
  __shared__ float scratch[4];
  float sum = block_sum256(xv.x + xv.y + xv.z + xv.w, scratch);
  float ssq = block_sum256(xv.x*xv.x + xv.y*xv.y + xv.z*xv.z + xv.w*xv.w, scratch);
  float mu = sum * (1.0f / DD);
  float var = ssq * (1.0f / DD) - mu * mu;
  float rstd = rsqrtf(var + 1e-5f);
  float4 wv = *(const float4*)(w + t * 4), bv = *(const float4*)(b + t * 4);
  float y0 = (xv.x - mu) * rstd * wv.x + bv.x;
  float y1 = (xv.y - mu) * rstd * wv.y + bv.y;
  float y2 = (xv.z - mu) * rstd * wv.z + bv.z;
  float y3 = (xv.w - mu) * rstd * wv.w + bv.w;
  float n2 = block_sum256(y0*y0 + y1*y1 + y2*y2 + y3*y3, scratch);
  float inv = 1.0f / (sqrtf(n2) + 1e-12f);
  ushort4 o;
  o.x = f2bf(y0 * inv); o.y = f2bf(y1 * inv);
  o.z = f2bf(y2 * inv); o.w = f2bf(y3 * inv);
  *(ushort4*)(uhi + base) = o;
}

// ---------------- loss: combine per-wave sum-exp partials (500 per row) --------------
__global__ void lse_reduce_kernel(const float* __restrict__ psum,
                                  const float* __restrict__ logits, const int* __restrict__ labels,
                                  float* __restrict__ lrow){
  int idx = blockIdx.x;               // 0..4093
  int b = idx / (SS - 1), qq = idx - b * (SS - 1);
  int row = b * SS + qq;
  int t = threadIdx.x;                // 64 threads
  float l = 0.f;
  for (int p = t; p < 500; p += 64) l += psum[((long)row << 9) + p];
  #pragma unroll
  for (int o = 1; o < 64; o <<= 1) l += __shfl_xor(l, o, 64);
  if (t == 0){
    float lse = __logf(l);
    float tl = logits[(long)row * VV + labels[row + 1]];
    lrow[idx] = lse - tl;
  }
}

__global__ void loss_reduce_kernel(const float* __restrict__ lrow, float* __restrict__ dst){
  __shared__ float scratch[4];
  float s = 0.f;
  for (int j = threadIdx.x; j < BB * (SS - 1); j += 256) s += lrow[j];
  float tot = block_sum256(s, scratch);
  if (threadIdx.x == 0) dst[0] = tot / (float)(BB * (SS - 1));
}

// ---------------- launch ------------------------------------------------------------
extern "C" void kernel_launch(void* const* d_in, const int* in_sizes, int n_in,
                              void* d_out, int out_size, void* d_ws, size_t ws_size,
                              hipStream_t stream) {
  const int*   ids    = (const int*)d_in[0];
  const int*   labels = (const int*)d_in[1];
  const float* proj_w = (const float*)d_in[2];
  const float* proj_b = (const float*)d_in[3];
  const float* ln_w   = (const float*)d_in[4];
  const float* ln_b   = (const float*)d_in[5];
  const float* fln_w  = (const float*)d_in[6];
  const float* fln_b  = (const float*)d_in[7];
  const float* out_w  = (const float*)d_in[8];
  float* out = (float*)d_out;

  char* ws = (char*)d_ws;
  float*          s_f32 = (float*)(ws + 0);                    // 16.78 MB
  unsigned short* op_hi = (unsigned short*)(ws + 16777216);    //  8.39 MB
  unsigned short* op_lo = (unsigned short*)(ws + 25165824);    //  8.39 MB
  unsigned short* T_hi  = (unsigned short*)(ws + 33554432);    //  8.39 MB
  unsigned short* T_lo  = (unsigned short*)(ws + 41943040);    //  8.39 MB
  float*          k1    = (float*)(ws + 50331648);             // 16.78 MB
  float*          k2    = (float*)(ws + 67108864);             // 16.78 MB (k1b/hb home)
  unsigned short* sc_hi = (unsigned short*)(ws + 83886080);    //  8.39 MB
  unsigned short* sc_lo = (unsigned short*)(ws + 92274688);    //  8.39 MB
  unsigned short* WhiT  = (unsigned short*)(ws + 100663296);   // 16.78 MB [L][n][k]
  unsigned short* WloT  = (unsigned short*)(ws + 117440512);   // 16.78 MB
  float*          energy= (float*)(ws + 134217728);
  float*          lrow  = (float*)(ws + 134234368);
  unsigned short* owT   = T_hi;  // 65.54 MB overlay (dead zone at vocab time)
  float*          psum  = (float*)(ws + 0);          // overlays s_f32 (dead after fln)
  float*          k1b   = k2;                        // k2 buffer dead during PV1
  float*          k2b   = (float*)(ws + 16777216);   // op region dead during PV2
  float*          hb    = k2;                        // proj ks=1 partial (ev dead post-tunnel)

  // proj_w [L][k][n] -> WhiT/WloT [L][n][k] (fp32-split bf16)
  transpose_f32_bf16_kernel<true><<<dim3(16, 16, 8), 256, 0, stream>>>(proj_w, WhiT, WloT, DD, DD);
  // encode
  encode_kernel<<<NROWS, 256, 0, stream>>>(ids, s_f32, op_hi, op_lo);
  transpose_bf16_pair_kernel<<<dim3(16, 32, 4), 256, 0, stream>>>(op_hi, op_lo, T_hi, T_lo, SS, DD);

  for (int l = 0; l < LL; ++l){
    // score1 = tril(states @ statesT)/32  -> bf16 hi/lo
    gemm_nt_kernel<2, 1><<<dim3(256, 2), 512, 0, stream>>>(
        op_hi, op_lo, op_hi, op_lo, nullptr, sc_hi, sc_lo, nullptr,
        DD, DD, DD, SS, 16, 16, (long)SS * DD, (long)SS * DD, (long)SS * SS, 0.03125f);
    // k1 = score1 @ states  (split-K: ks0 -> k1, ks1 -> k1b)
    gemm_nt_kernel<5, 3><<<dim3(192, 2), 512, 0, stream>>>(
        sc_hi, sc_lo, T_hi, T_lo, k1, (unsigned short*)k1b, nullptr, nullptr,
        SS, SS, SS, DD, 24, 8, (long)SS * SS, (long)DD * SS, (long)SS * DD, 1.0f);
    // combine + mid = s + dt*k1 -> op hi/lo + T hi/lo (transpose fused)
    mid_trans_kernel<<<dim3(16, 64), 256, 0, stream>>>(s_f32, k1, k1b, op_hi, op_lo, T_hi, T_lo);
    // score2 = tril(mid @ midT)/32
    gemm_nt_kernel<2, 1><<<dim3(256, 2), 512, 0, stream>>>(
        op_hi, op_lo, op_hi, op_lo, nullptr, sc_hi, sc_lo, nullptr,
        DD, DD, DD, SS, 16, 16, (long)SS * DD, (long)SS * DD, (long)SS * SS, 0.03125f);
    // k2 = score2 @ mid  (split-K: ks0 -> k2, ks1 -> k2b)
    gemm_nt_kernel<5, 3><<<dim3(192, 2), 512, 0, stream>>>(
        sc_hi, sc_lo, T_hi, T_lo, k2, (unsigned short*)k2b, nullptr, nullptr,
        SS, SS, SS, DD, 24, 8, (long)SS * SS, (long)DD * SS, (long)SS * DD, 1.0f);
    // ev = s + 0.5dt*(k1 + k2a + k2b) (into k2) + row energies
    ev_energy_kernel<<<NROWS, 256, 0, stream>>>(s_f32, k1, k2, k2b, energy);
    // tunneling (batch-mean fused; bit-identical thr arithmetic)
    tunnel_kernel<<<NROWS, 256, 0, stream>>>(k2, energy, op_hi, op_lo);
    // h = ev @ proj_w[l] + proj_b[l]  (split-K uniform: ks0+bias -> k1, ks1 -> hb=k2)
    gemm_nt_kernel<0, 4><<<dim3(512, 1), 512, 0, stream>>>(
        op_hi, op_lo, WhiT + (long)l * DD * DD, WloT + (long)l * DD * DD,
        k1, (unsigned short*)hb, nullptr, proj_b + l * DD,
        DD, DD, DD, DD, 32, 8, 0, 0, 0, 1.0f);
    // states = LN(k1 + hb)
    ln_kernel<<<NROWS, 256, 0, stream>>>(k1, hb, ln_w + l * DD, ln_b + l * DD, s_f32, op_hi, op_lo);
    if (l < LL - 1){
      transpose_bf16_pair_kernel<<<dim3(16, 32, 4), 256, 0, stream>>>(op_hi, op_lo, T_hi, T_lo, SS, DD);
    }
  }

  // out_w [k][v] -> owT [v][k] bf16 (plain); u = unit(LN(states)) -> op_hi
  transpose_f32_bf16_kernel<false><<<dim3(500, 16, 1), 256, 0, stream>>>(out_w, owT, nullptr, DD, VV);
  fln_kernel<<<NROWS, 256, 0, stream>>>(s_f32, fln_w, fln_b, op_hi);
  // logits = u @ out_w  (128^2, 2 blocks/CU) + fused max-free sum-exp partials
  gemm256_kernel<<<8000, 512, 0, stream>>>(op_hi, owT, out, psum);
  // loss from partials
  lse_reduce_kernel<<<BB * (SS - 1), 64, 0, stream>>>(psum, out, labels, lrow);
  loss_reduce_kernel<<<1, 256, 0, stream>>>(lrow, out + (long)NROWS * VV);
}

// Round 16
// 2400.974 us; speedup vs baseline: 1.0584x; 1.0584x over previous
//
#include <hip/hip_runtime.h>

#define LL 8
#define DD 1024
#define VV 32000
#define SS 2048
#define BB 2
#define NROWS 4096          // B*S
#define DT_STEP 0.055f      // 0.5*(dt_min+dt_max)
#define HALF_DT 0.0275f
#define TUNNEL_SCALE 1.55f  // 1 + dt/dt_max

typedef __attribute__((ext_vector_type(8))) short bf16x8;
typedef __attribute__((ext_vector_type(4))) float f32x4;

static __device__ __forceinline__ float bf2f(unsigned short u){
  union { unsigned int i; float f; } v; v.i = ((unsigned int)u) << 16; return v.f;
}
static __device__ __forceinline__ unsigned short f2bf(float f){
  union { float f; unsigned int i; } v; v.f = f;
  unsigned int r = v.i + 0x7fffu + ((v.i >> 16) & 1u);
  return (unsigned short)(r >> 16);
}

// async global->LDS, 16B per lane. lds dest must be wave-uniform base; HW adds lane*16.
static __device__ __forceinline__ void gl16(const unsigned short* g, unsigned short* l){
  __builtin_amdgcn_global_load_lds(
      (const __attribute__((address_space(1))) unsigned int*)g,
      (__attribute__((address_space(3))) unsigned int*)l, 16, 0, 0);
}

__device__ __forceinline__ float block_sum256(float v, volatile float* scratch){
  #pragma unroll
  for (int off = 32; off; off >>= 1) v += __shfl_down(v, off, 64);
  int w = threadIdx.x >> 6, lane = threadIdx.x & 63;
  __syncthreads();
  if (lane == 0) scratch[w] = v;
  __syncthreads();
  return scratch[0] + scratch[1] + scratch[2] + scratch[3];
}

// ---------------- encode: phase embedding -> f32 master + bf16 hi/lo ----------------
__global__ void encode_kernel(const int* __restrict__ ids, float* __restrict__ s_f32,
                              unsigned short* __restrict__ hi, unsigned short* __restrict__ lo){
  int row = blockIdx.x;            // 0..4095 = b*S+s
  int t = threadIdx.x;
  float theta = 6.28318530717958647692f * (float)ids[row] / 32000.0f;
  #pragma unroll
  for (int i = 0; i < 2; ++i){
    int kk = t + i * 256;          // 0..511
    float ang = theta * (float)(kk + 1);
    float sv, cv; sincosf(ang, &sv, &cv);
    float c = cv * 0.03125f, s = sv * 0.03125f;   // 1/sqrt(D)
    long b0 = (long)row * DD + kk, b1 = b0 + 512;
    s_f32[b0] = c; s_f32[b1] = s;
    unsigned short ch = f2bf(c); hi[b0] = ch; lo[b0] = f2bf(c - bf2f(ch));
    unsigned short sh = f2bf(s); hi[b1] = sh; lo[b1] = f2bf(s - bf2f(sh));
  }
}

// ---------------- bf16 tiled transpose (hi+lo pair): [b][R][C] -> [b][C][R] ----------
__global__ void transpose_bf16_pair_kernel(const unsigned short* __restrict__ in_hi,
                                           const unsigned short* __restrict__ in_lo,
                                           unsigned short* __restrict__ out_hi,
                                           unsigned short* __restrict__ out_lo,
                                           int R, int C){
  __shared__ __align__(16) unsigned short tile[64][80];
  int zz = blockIdx.z;                       // (batch<<1) | sel
  const unsigned short* in = (zz & 1) ? in_lo : in_hi;
  unsigned short* out = (zz & 1) ? out_lo : out_hi;
  long ib = (long)(zz >> 1) * R * C;
  int c0 = blockIdx.x * 64, r0 = blockIdx.y * 64;
  int t = threadIdx.x;
  #pragma unroll
  for (int i = 0; i < 2; ++i){
    int j = t + i * 256; int row = j >> 3, cc = j & 7;
    *(uint4*)&tile[row][cc * 8] = *(const uint4*)(in + ib + (long)(r0 + row) * C + c0 + cc * 8);
  }
  __syncthreads();
  #pragma unroll
  for (int i = 0; i < 2; ++i){
    int j = t + i * 256; int orow = j >> 3, cc = j & 7;
    union { unsigned short u[8]; uint4 v; } tmp;
    #pragma unroll
    for (int e = 0; e < 8; ++e) tmp.u[e] = tile[cc * 8 + e][orow];
    *(uint4*)(out + ib + (long)(c0 + orow) * R + r0 + cc * 8) = tmp.v;
  }
}

// -------- f32 -> bf16 (optionally hi/lo split) transposing convert --------------------
template<bool SPLIT>
__global__ void transpose_f32_bf16_kernel(const float* __restrict__ in,
                                          unsigned short* __restrict__ ohi,
                                          unsigned short* __restrict__ olo, int R, int C){
  __shared__ float tile[64][68];
  long ib = (long)blockIdx.z * R * C;
  int c0 = blockIdx.x * 64, r0 = blockIdx.y * 64;
  int t = threadIdx.x;
  #pragma unroll
  for (int i = 0; i < 4; ++i){
    int j = t + i * 256; int row = j >> 4, cc = j & 15;
    *(float4*)&tile[row][cc * 4] = *(const float4*)(in + ib + (long)(r0 + row) * C + c0 + cc * 4);
  }
  __syncthreads();
  #pragma unroll
  for (int i = 0; i < 2; ++i){
    int j = t + i * 256; int orow = j >> 3, cc = j & 7;
    union { unsigned short u[8]; uint4 v; } th, tl;
    #pragma unroll
    for (int e = 0; e < 8; ++e){
      float v = tile[cc * 8 + e][orow];
      unsigned short h = f2bf(v); th.u[e] = h;
      if (SPLIT) tl.u[e] = f2bf(v - bf2f(h));
    }
    long ob = ib + (long)(c0 + orow) * R + r0 + cc * 8;
    *(uint4*)(ohi + ob) = th.v;
    if (SPLIT) *(uint4*)(olo + ob) = tl.v;
  }
}

// ---------------- split NT GEMM (128x128, 8 waves, dbuf, 2-phase): C = alpha*A@B^T ----
// r11-proven 2-phase fine interleave. Operands (hi,lo) bf16 pairs -> 3 MFMA products.
// OUTMODE: 0 = f32 C (+bias); 2 = bf16 hi/lo (score); 5 = plain f32 to (ks? C2 : C)
// CAUSAL: 0 none; 1 score (unused now); 2 pv k-limit; 3 split-K pv; 4 split-K uniform.
template<int OUTMODE, int CAUSAL>
__global__ __launch_bounds__(512, 4)
void gemm_nt_kernel(const unsigned short* __restrict__ Ahi, const unsigned short* __restrict__ Alo,
                    const unsigned short* __restrict__ Bhi, const unsigned short* __restrict__ Blo,
                    float* __restrict__ C, unsigned short* __restrict__ Chi,
                    unsigned short* __restrict__ Clo, const float* __restrict__ bias,
                    int K, int lda, int ldb, int ldc, int MT, int NT,
                    long batchA, long batchB, long batchC, float alpha)
{
  const int bz = blockIdx.y;
  int mt, nt, ks = 0;
  {
    const int nwg = (CAUSAL == 4) ? (MT * NT * 2) : (MT * NT);
    const int q = nwg >> 3, r = nwg & 7;
    const int xcd = blockIdx.x & 7, off = blockIdx.x >> 3;
    const int wg = (xcd < r ? xcd * (q + 1) : r * (q + 1) + (xcd - r) * q) + off;
    if (CAUSAL == 3){
      if (wg < 128){ ks = 0; mt = wg >> 3; nt = wg & 7; }
      else { int w2 = wg - 128; ks = 1; mt = 8 + (w2 >> 3); nt = w2 & 7; }
    } else if (CAUSAL == 4){
      int w2 = wg; ks = 0;
      if (w2 >= MT * NT){ ks = 1; w2 -= MT * NT; }
      mt = w2 / NT; nt = w2 - mt * NT;
    } else {
      const int band = wg / (NT << 3), rem = wg - band * (NT << 3);
      mt = (band << 3) + (rem & 7); nt = rem >> 3;
    }
  }
  if (CAUSAL == 1 && nt > mt) return;
  const int m0 = mt << 7, n0 = nt << 7;
  int kstart = 0, kend = K;
  if (CAUSAL == 2){ int kl = (mt + 1) << 7; kend = kl < K ? kl : K; }
  if (CAUSAL == 3){
    kstart = ks << 10;
    int kl = (mt + 1) << 7, kc = kstart + 1024;
    kend = kl < kc ? kl : kc;
  }
  if (CAUSAL == 4){
    kstart = ks * (K >> 1);
    kend = kstart + (K >> 1);
  }

  __shared__ __align__(16) unsigned short sA[2][128][64];
  __shared__ __align__(16) unsigned short sB[2][128][64];

  const int tid = threadIdx.x;
  const int lane = tid & 63;
  const int w = tid >> 6;              // 0..7
  const int wr = w >> 2, wc = w & 3;   // 2 x 4 wave grid, 64x32 per wave
  const int fr = lane & 15, fc = lane >> 4;
  const int fr7 = fr & 7;

  f32x4 acc[4][2];
  #pragma unroll
  for (int i = 0; i < 4; ++i)
    #pragma unroll
    for (int j = 0; j < 2; ++j) acc[i][j] = (f32x4){0.f, 0.f, 0.f, 0.f};

  const int srow = tid >> 3, slot = tid & 7;
  const int cont = slot ^ (srow & 7);         // content chunk at this slot
  const long aoff = (long)bz * batchA, boff = (long)bz * batchB;
  const int gcol = (cont & 3) << 3;
  const unsigned short* gA = (cont >= 4 ? Alo : Ahi) + aoff + (long)(m0 + srow) * lda + gcol;
  const unsigned short* gB = (cont >= 4 ? Blo : Bhi) + boff + (long)(n0 + srow) * ldb + gcol;
  const long rstepA = 64L * lda, rstepB = 64L * ldb;
  const int wofs = w << 9;                    // wave base: w*8 rows * 64 elems

  const int oh = (fc ^ fr7) << 4;
  const int ol = ((4 + fc) ^ fr7) << 4;

  const int ntiles = (kend - kstart) >> 5;

  // prologue: stage tile 0 fully (A0,A1,B0,B1 in that order)
  gl16(gA + kstart,          &sA[0][0][0] + wofs);
  gl16(gA + kstart + rstepA, &sA[0][0][0] + 4096 + wofs);
  gl16(gB + kstart,          &sB[0][0][0] + wofs);
  gl16(gB + kstart + rstepB, &sB[0][0][0] + 4096 + wofs);

  int cur = 0;
  for (int t = 0; t < ntiles; ++t){
    const bool stg = (t < ntiles - 1);
    const long nk = kstart + ((long)(t + 1) << 5);
    const char* bA_ = (const char*)&sA[cur][0][0];
    const char* bB_ = (const char*)&sB[cur][0][0];
    bf16x8 ah_[4], al_[4];

    // ---- phase 0: stage A of t+1; certify tile t; read A-frags + B ni=0; 12 MFMA ----
    if (stg){
      gl16(gA + nk,          &sA[cur ^ 1][0][0] + wofs);
      gl16(gA + nk + rstepA, &sA[cur ^ 1][0][0] + 4096 + wofs);
      asm volatile("s_waitcnt vmcnt(2)" ::: "memory");   // tile-t's 4 loads landed
    } else {
      asm volatile("s_waitcnt vmcnt(0)" ::: "memory");
    }
    asm volatile("s_barrier" ::: "memory");              // cross-wave certify
    #pragma unroll
    for (int mi = 0; mi < 4; ++mi){
      const char* p_ = bA_ + (wr * 64 + mi * 16 + fr) * 128;
      ah_[mi] = *(const bf16x8*)(p_ + oh);
      al_[mi] = *(const bf16x8*)(p_ + ol);
    }
    {
      const char* pb_ = bB_ + (wc * 32 + fr) * 128;
      bf16x8 bh_ = *(const bf16x8*)(pb_ + oh);
      bf16x8 bl_ = *(const bf16x8*)(pb_ + ol);
      __builtin_amdgcn_s_setprio(1);
      #pragma unroll
      for (int mi = 0; mi < 4; ++mi){
        acc[mi][0] = __builtin_amdgcn_mfma_f32_16x16x32_bf16(ah_[mi], bh_, acc[mi][0], 0, 0, 0);
        acc[mi][0] = __builtin_amdgcn_mfma_f32_16x16x32_bf16(ah_[mi], bl_, acc[mi][0], 0, 0, 0);
        acc[mi][0] = __builtin_amdgcn_mfma_f32_16x16x32_bf16(al_[mi], bh_, acc[mi][0], 0, 0, 0);
      }
      __builtin_amdgcn_s_setprio(0);
    }

    // ---- phase 1: stage B of t+1; barrier; read B ni=1; 12 MFMA ----------------------
    if (stg){
      gl16(gB + nk,          &sB[cur ^ 1][0][0] + wofs);
      gl16(gB + nk + rstepB, &sB[cur ^ 1][0][0] + 4096 + wofs);
    }
    asm volatile("s_barrier" ::: "memory");
    {
      const char* pb_ = bB_ + (wc * 32 + 16 + fr) * 128;
      bf16x8 bh_ = *(const bf16x8*)(pb_ + oh);
      bf16x8 bl_ = *(const bf16x8*)(pb_ + ol);
      __builtin_amdgcn_s_setprio(1);
      #pragma unroll
      for (int mi = 0; mi < 4; ++mi){
        acc[mi][1] = __builtin_amdgcn_mfma_f32_16x16x32_bf16(ah_[mi], bh_, acc[mi][1], 0, 0, 0);
        acc[mi][1] = __builtin_amdgcn_mfma_f32_16x16x32_bf16(ah_[mi], bl_, acc[mi][1], 0, 0, 0);
        acc[mi][1] = __builtin_amdgcn_mfma_f32_16x16x32_bf16(al_[mi], bh_, acc[mi][1], 0, 0, 0);
      }
      __builtin_amdgcn_s_setprio(0);
    }
    cur ^= 1;
  }

  const long coff = (long)bz * batchC;
  float* Cout = ((OUTMODE == 5 || CAUSAL == 4) && ks) ? (float*)Chi : C;
  const int rb0 = m0 + wr * 64 + fc * 4;   // + mi*16 + rg
  const int cb0 = n0 + wc * 32 + fr;       // + ni*16
  #pragma unroll
  for (int mi = 0; mi < 4; ++mi){
    #pragma unroll
    for (int ni = 0; ni < 2; ++ni){
      #pragma unroll
      for (int rg = 0; rg < 4; ++rg){
        int row = rb0 + mi * 16 + rg;
        int col = cb0 + ni * 16;
        float v = acc[mi][ni][rg] * alpha;
        long idx = coff + (long)row * ldc + col;
        if (OUTMODE == 0){
          if (bias && ks == 0) v += bias[col];   // bias only in the ks=0 partial
          Cout[idx] = v;
        } else if (OUTMODE == 2){
          if (CAUSAL == 1 && col > row) v = 0.0f;
          unsigned short h = f2bf(v);
          Chi[idx] = h;
          Clo[idx] = f2bf(v - bf2f(h));
        } else {                                    // OUTMODE 5: plain partial store
          Cout[idx] = v;
        }
      }
    }
  }
}

// ---------------- causal score GEMM, 128x64 tiles (r16): sc = tril(A@A^T)*alpha -------
// Exactly the 272 active causal tiles per batch (no wasted blocks); 544 half-cost
// blocks at 3 blocks/CU capacity (48 KB LDS) -> worst CU 1.5 units vs 2.0 for the
// old 272x full-tile launch. Same r11 2-phase schedule / swizzle / K-order.
// 8 waves in 4x2 grid, 32x32 of C per wave. Output bf16 hi/lo with causal mask.
__global__ __launch_bounds__(512, 4)
void score64_kernel(const unsigned short* __restrict__ Ahi, const unsigned short* __restrict__ Alo,
                    unsigned short* __restrict__ Chi, unsigned short* __restrict__ Clo,
                    float alpha)
{
  const int bz = blockIdx.y;
  // XCD swizzle over 272 (q=34, r=0) then triangular map: wg in [mt^2+mt, (mt+1)^2+(mt+1))
  const int wg = (blockIdx.x & 7) * 34 + (blockIdx.x >> 3);
  int mt = (int)((sqrtf(4.0f * wg + 1.0f) - 1.0f) * 0.5f);
  while (mt * mt + mt > wg) --mt;
  while ((mt + 1) * (mt + 1) + (mt + 1) <= wg) ++mt;
  const int nt = wg - mt * mt - mt;          // 0..2mt+1
  const int m0 = mt << 7, n0 = nt << 6;

  __shared__ __align__(16) unsigned short sA[2][128][64];   // 32 KB
  __shared__ __align__(16) unsigned short sB[2][64][64];    // 16 KB

  const int tid = threadIdx.x;
  const int lane = tid & 63;
  const int w = tid >> 6;
  const int wr = w >> 1, wc = w & 1;         // 4 x 2 wave grid, 32x32 per wave
  const int fr = lane & 15, fc = lane >> 4;
  const int fr7 = fr & 7;

  f32x4 acc[2][2];
  #pragma unroll
  for (int i = 0; i < 2; ++i)
    #pragma unroll
    for (int j = 0; j < 2; ++j) acc[i][j] = (f32x4){0.f, 0.f, 0.f, 0.f};

  const int srow = tid >> 3, slot = tid & 7;  // srow 0..63
  const int cont = slot ^ (srow & 7);
  const long boffs = (long)bz * SS * DD;
  const int gcol = (cont & 3) << 3;
  const unsigned short* gA = (cont >= 4 ? Alo : Ahi) + boffs + (long)(m0 + srow) * DD + gcol;
  const unsigned short* gB = (cont >= 4 ? Alo : Ahi) + boffs + (long)(n0 + srow) * DD + gcol;
  const long rstepA = 64L * DD;
  const int wofs = w << 9;                    // w*8 rows * 64 elems

  const int oh = (fc ^ fr7) << 4;
  const int ol = ((4 + fc) ^ fr7) << 4;

  // prologue: tile 0 = A(2 issues) + B(1 issue)
  gl16(gA,          &sA[0][0][0] + wofs);
  gl16(gA + rstepA, &sA[0][0][0] + 4096 + wofs);
  gl16(gB,          &sB[0][0][0] + wofs);

  int cur = 0;
  for (int t = 0; t < 32; ++t){
    const bool stg = (t < 31);
    const long nk = (long)(t + 1) << 5;
    const char* bA_ = (const char*)&sA[cur][0][0];
    const char* bB_ = (const char*)&sB[cur][0][0];
    bf16x8 ah_[2], al_[2];

    // ---- phase 0: stage A of t+1 (2); certify tile t (3 loads); A-frags + B ni=0 ----
    if (stg){
      gl16(gA + nk,          &sA[cur ^ 1][0][0] + wofs);
      gl16(gA + nk + rstepA, &sA[cur ^ 1][0][0] + 4096 + wofs);
      asm volatile("s_waitcnt vmcnt(2)" ::: "memory");
    } else {
      asm volatile("s_waitcnt vmcnt(0)" ::: "memory");
    }
    asm volatile("s_barrier" ::: "memory");
    #pragma unroll
    for (int mi = 0; mi < 2; ++mi){
      const char* p_ = bA_ + (wr * 32 + mi * 16 + fr) * 128;
      ah_[mi] = *(const bf16x8*)(p_ + oh);
      al_[mi] = *(const bf16x8*)(p_ + ol);
    }
    {
      const char* pb_ = bB_ + (wc * 32 + fr) * 128;
      bf16x8 bh_ = *(const bf16x8*)(pb_ + oh);
      bf16x8 bl_ = *(const bf16x8*)(pb_ + ol);
      __builtin_amdgcn_s_setprio(1);
      #pragma unroll
      for (int mi = 0; mi < 2; ++mi){
        acc[mi][0] = __builtin_amdgcn_mfma_f32_16x16x32_bf16(ah_[mi], bh_, acc[mi][0], 0, 0, 0);
        acc[mi][0] = __builtin_amdgcn_mfma_f32_16x16x32_bf16(ah_[mi], bl_, acc[mi][0], 0, 0, 0);
        acc[mi][0] = __builtin_amdgcn_mfma_f32_16x16x32_bf16(al_[mi], bh_, acc[mi][0], 0, 0, 0);
      }
      __builtin_amdgcn_s_setprio(0);
    }

    // ---- phase 1: stage B of t+1 (1); barrier; B ni=1 ----
    if (stg){
      gl16(gB + nk, &sB[cur ^ 1][0][0] + wofs);
    }
    asm volatile("s_barrier" ::: "memory");
    {
      const char* pb_ = bB_ + (wc * 32 + 16 + fr) * 128;
      bf16x8 bh_ = *(const bf16x8*)(pb_ + oh);
      bf16x8 bl_ = *(const bf16x8*)(pb_ + ol);
      __builtin_amdgcn_s_setprio(1);
      #pragma unroll
      for (int mi = 0; mi < 2; ++mi){
        acc[mi][1] = __builtin_amdgcn_mfma_f32_16x16x32_bf16(ah_[mi], bh_, acc[mi][1], 0, 0, 0);
        acc[mi][1] = __builtin_amdgcn_mfma_f32_16x16x32_bf16(ah_[mi], bl_, acc[mi][1], 0, 0, 0);
        acc[mi][1] = __builtin_amdgcn_mfma_f32_16x16x32_bf16(al_[mi], bh_, acc[mi][1], 0, 0, 0);
      }
      __builtin_amdgcn_s_setprio(0);
    }
    cur ^= 1;
  }

  const long coff = (long)bz * SS * SS;
  const int rb0 = m0 + wr * 32 + fc * 4;
  const int cb0 = n0 + wc * 32 + fr;
  #pragma unroll
  for (int mi = 0; mi < 2; ++mi){
    #pragma unroll
    for (int ni = 0; ni < 2; ++ni){
      #pragma unroll
      for (int rg = 0; rg < 4; ++rg){
        int row = rb0 + mi * 16 + rg;
        int col = cb0 + ni * 16;
        float v = acc[mi][ni][rg] * alpha;
        if (col > row) v = 0.0f;             // causal mask
        long idx = coff + (long)row * SS + col;
        unsigned short h = f2bf(v);
        Chi[idx] = h;
        Clo[idx] = f2bf(v - bf2f(h));
      }
    }
  }
}

// ---------------- 128x128 vocab GEMM, 2 blocks/CU: C = A @ B^T + LSE partials ---------
__global__ __launch_bounds__(512, 4)
void gemm256_kernel(const unsigned short* __restrict__ A,    // [4096][1024] bf16
                    const unsigned short* __restrict__ Bt,   // [32000][1024] bf16
                    float* __restrict__ C,                   // [4096][32000] f32
                    float* __restrict__ psum)                // [4096][512] (500 used)
{
  const int MT = 32, NT = 250;
  const int nwg = MT * NT;                 // 8000
  const int q = nwg >> 3;                  // 1000, r = 0
  const int xcd = blockIdx.x & 7, off = blockIdx.x >> 3;
  const int wg = xcd * q + off;
  const int band = wg / (NT << 3), rem = wg - band * (NT << 3);
  const int mt = (band << 3) + (rem & 7), nt = rem >> 3;
  const int m0 = mt << 7, n0 = nt << 7;

  __shared__ __align__(16) unsigned short sA[2][128][64];   // 32 KB
  __shared__ __align__(16) unsigned short sB[2][128][64];   // 32 KB

  const int tid = threadIdx.x;
  const int lane = tid & 63;
  const int w = tid >> 6;
  const int wr = w >> 1, wc = w & 1;       // 4 x 2 wave grid, 32x64 per wave
  const int fr = lane & 15, fc = lane >> 4;
  const int fr7 = fr & 7;

  f32x4 acc[2][4];
  #pragma unroll
  for (int i = 0; i < 2; ++i)
    #pragma unroll
    for (int j = 0; j < 4; ++j) acc[i][j] = (f32x4){0.f, 0.f, 0.f, 0.f};

  const int srow = tid >> 3, slot = tid & 7;   // srow 0..63
  const int cont = slot ^ (srow & 7);
  const unsigned short* gA = A  + (long)(m0 + srow) * DD + (cont << 3);
  const unsigned short* gB = Bt + (long)(n0 + srow) * DD + (cont << 3);
  const long rstep = 64L * DD;
  const int wofs = w << 9;                 // w*8 rows * 64 elems

  const int oh = (fc ^ fr7) << 4;          // ks=0 chunk
  const int ol = ((4 + fc) ^ fr7) << 4;    // ks=1 chunk

  // prologue: stage tile 0 fully (A0,A1,B0,B1)
  gl16(gA,         &sA[0][0][0] + wofs);
  gl16(gA + rstep, &sA[0][0][0] + 4096 + wofs);
  gl16(gB,         &sB[0][0][0] + wofs);
  gl16(gB + rstep, &sB[0][0][0] + 4096 + wofs);

  int cur = 0;
  for (int t = 0; t < 16; ++t){
    const bool stg = (t < 15);
    const long nk = (long)(t + 1) << 6;    // BK=64
    const char* bA_ = (const char*)&sA[cur][0][0];
    const char* bB_ = (const char*)&sB[cur][0][0];
    bf16x8 aq[2][2], bq[4][2];

    // ---- phase 0: stage A of t+1; certify tile t; read A + B ni=0,1; 8 MFMA ----
    if (stg){
      gl16(gA + nk,         &sA[cur ^ 1][0][0] + wofs);
      gl16(gA + nk + rstep, &sA[cur ^ 1][0][0] + 4096 + wofs);
      asm volatile("s_waitcnt vmcnt(2)" ::: "memory");
    } else {
      asm volatile("s_waitcnt vmcnt(0)" ::: "memory");
    }
    asm volatile("s_barrier" ::: "memory");
    #pragma unroll
    for (int mi = 0; mi < 2; ++mi){
      const char* p = bA_ + (wr * 32 + mi * 16 + fr) * 128;
      aq[mi][0] = *(const bf16x8*)(p + oh);
      aq[mi][1] = *(const bf16x8*)(p + ol);
    }
    #pragma unroll
    for (int ni = 0; ni < 2; ++ni){
      const char* p = bB_ + (wc * 64 + ni * 16 + fr) * 128;
      bq[ni][0] = *(const bf16x8*)(p + oh);
      bq[ni][1] = *(const bf16x8*)(p + ol);
    }
    __builtin_amdgcn_s_setprio(1);
    #pragma unroll
    for (int ks = 0; ks < 2; ++ks)
      #pragma unroll
      for (int mi = 0; mi < 2; ++mi)
        #pragma unroll
        for (int ni = 0; ni < 2; ++ni)
          acc[mi][ni] = __builtin_amdgcn_mfma_f32_16x16x32_bf16(aq[mi][ks], bq[ni][ks], acc[mi][ni], 0, 0, 0);
    __builtin_amdgcn_s_setprio(0);

    // ---- phase 1: stage B of t+1; barrier; read B ni=2,3; 8 MFMA ----
    if (stg){
      gl16(gB + nk,         &sB[cur ^ 1][0][0] + wofs);
      gl16(gB + nk + rstep, &sB[cur ^ 1][0][0] + 4096 + wofs);
    }
    asm volatile("s_barrier" ::: "memory");
    #pragma unroll
    for (int ni = 2; ni < 4; ++ni){
      const char* p = bB_ + (wc * 64 + ni * 16 + fr) * 128;
      bq[ni][0] = *(const bf16x8*)(p + oh);
      bq[ni][1] = *(const bf16x8*)(p + ol);
    }
    __builtin_amdgcn_s_setprio(1);
    #pragma unroll
    for (int ks = 0; ks < 2; ++ks)
      #pragma unroll
      for (int mi = 0; mi < 2; ++mi)
        #pragma unroll
        for (int ni = 2; ni < 4; ++ni)
          acc[mi][ni] = __builtin_amdgcn_mfma_f32_16x16x32_bf16(aq[mi][ks], bq[ni][ks], acc[mi][ni], 0, 0, 0);
    __builtin_amdgcn_s_setprio(0);

    cur ^= 1;
  }

  const int rb0 = m0 + wr * 32 + fc * 4;
  const int cb0 = n0 + wc * 64 + fr;
  #pragma unroll
  for (int mi = 0; mi < 2; ++mi){
    #pragma unroll
    for (int ni = 0; ni < 4; ++ni){
      #pragma unroll
      for (int rg = 0; rg < 4; ++rg){
        C[(long)(rb0 + mi * 16 + rg) * VV + cb0 + ni * 16] = acc[mi][ni][rg];
      }
    }
  }

  // max-free sum-exp partials: |logit| <= ~0.7, exp cannot overflow.
  #pragma unroll
  for (int mi = 0; mi < 2; ++mi){
    #pragma unroll
    for (int rg = 0; rg < 4; ++rg){
      float s4 = __expf(acc[mi][0][rg]) + __expf(acc[mi][1][rg])
               + __expf(acc[mi][2][rg]) + __expf(acc[mi][3][rg]);
      #pragma unroll
      for (int o = 1; o < 16; o <<= 1) s4 += __shfl_xor(s4, o, 64);
      if (fr == 0){
        long pidx = ((long)(rb0 + mi * 16 + rg) << 9) + nt * 2 + wc;
        psum[pidx] = s4;
      }
    }
  }
}

// ---------------- combiners / elementwise --------------------------------------------
__global__ void mid_trans_kernel(const float* __restrict__ s, float* __restrict__ k1,
                                 const float* __restrict__ k1b,
                                 unsigned short* __restrict__ ohi, unsigned short* __restrict__ olo,
                                 unsigned short* __restrict__ thi, unsigned short* __restrict__ tlo){
  __shared__ float tile[64][68];
  int c0 = blockIdx.x * 64, r0g = blockIdx.y * 64;
  int t = threadIdx.x;
  #pragma unroll
  for (int i = 0; i < 4; ++i){
    int j = t + i * 256; int row = j >> 4, cc = (j & 15) * 4;
    long idx = (long)(r0g + row) * DD + c0 + cc;
    float4 a = *(const float4*)(k1 + idx);
    if (((r0g + row) & 2047) >= 1024){
      float4 b = *(const float4*)(k1b + idx);
      a.x += b.x; a.y += b.y; a.z += b.z; a.w += b.w;
    }
    *(float4*)(k1 + idx) = a;
    float4 sv = *(const float4*)(s + idx);
    float4 m;
    m.x = sv.x + DT_STEP * a.x; m.y = sv.y + DT_STEP * a.y;
    m.z = sv.z + DT_STEP * a.z; m.w = sv.w + DT_STEP * a.w;
    *(float4*)&tile[row][cc] = m;
    ushort4 hv, lv;
    hv.x = f2bf(m.x); lv.x = f2bf(m.x - bf2f(hv.x));
    hv.y = f2bf(m.y); lv.y = f2bf(m.y - bf2f(hv.y));
    hv.z = f2bf(m.z); lv.z = f2bf(m.z - bf2f(hv.z));
    hv.w = f2bf(m.w); lv.w = f2bf(m.w - bf2f(hv.w));
    *(ushort4*)(ohi + idx) = hv; *(ushort4*)(olo + idx) = lv;
  }
  __syncthreads();
  long tb = (long)(r0g >> 11) * DD * SS;
  int sb = r0g & 2047;
  #pragma unroll
  for (int i = 0; i < 2; ++i){
    int j = t + i * 256; int ocol = j >> 3, cc = (j & 7) * 8;
    union { unsigned short u[8]; uint4 v; } th, tl;
    #pragma unroll
    for (int e = 0; e < 8; ++e){
      float v = tile[cc + e][ocol];
      unsigned short h = f2bf(v);
      th.u[e] = h; tl.u[e] = f2bf(v - bf2f(h));
    }
    long ob = tb + (long)(c0 + ocol) * SS + sb + cc;
    *(uint4*)(thi + ob) = th.v;
    *(uint4*)(tlo + ob) = tl.v;
  }
}

__global__ void ev_energy_kernel(const float* __restrict__ s, const float* __restrict__ k1,
                                 float* __restrict__ k2, const float* __restrict__ k2b,
                                 float* __restrict__ energy){
  int row = blockIdx.x, t = threadIdx.x;
  long base = (long)row * DD + t * 4;
  float4 sv = *(const float4*)(s + base);
  float4 av = *(const float4*)(k1 + base);
  float4 bv = *(const float4*)(k2 + base);
  if ((row & 2047) >= 1024){
    float4 cv = *(const float4*)(k2b + base);
    bv.x += cv.x; bv.y += cv.y; bv.z += cv.z; bv.w += cv.w;
  }
  float4 ev;
  ev.x = sv.x + HALF_DT * (av.x + bv.x);
  ev.y = sv.y + HALF_DT * (av.y + bv.y);
  ev.z = sv.z + HALF_DT * (av.z + bv.z);
  ev.w = sv.w + HALF_DT * (av.w + bv.w);
  *(float4*)(k2 + base) = ev;
  __shared__ float scratch[4];
  float n2 = block_sum256(ev.x*ev.x + ev.y*ev.y + ev.z*ev.z + ev.w*ev.w, scratch);
  if (t == 0) energy[row] = sqrtf(n2);
}

__global__ void tunnel_kernel(const float* __restrict__ ev, const float* __restrict__ energy,
                              unsigned short* __restrict__ hi, unsigned short* __restrict__ lo){
  int row = blockIdx.x, t = threadIdx.x;
  const float* eb = energy + (row >> 11) * SS;
  float s = 0.f;
  for (int j = t; j < SS; j += 256) s += eb[j];
  __shared__ float scratch[4];
  float thr = block_sum256(s, scratch) * (1.0f / SS);
  float scale = (energy[row] < thr) ? TUNNEL_SCALE : 1.0f;
  long base = (long)row * DD + t * 4;
  float4 v = *(const float4*)(ev + base);
  v.x *= scale; v.y *= scale; v.z *= scale; v.w *= scale;
  ushort4 hv, lv;
  hv.x = f2bf(v.x); lv.x = f2bf(v.x - bf2f(hv.x));
  hv.y = f2bf(v.y); lv.y = f2bf(v.y - bf2f(hv.y));
  hv.z = f2bf(v.z); lv.z = f2bf(v.z - bf2f(hv.z));
  hv.w = f2bf(v.w); lv.w = f2bf(v.w - bf2f(hv.w));
  *(ushort4*)(hi + base) = hv; *(ushort4*)(lo + base) = lv;
}

__global__ void ln_kernel(const float* __restrict__ h, const float* __restrict__ hb,
                          const float* __restrict__ w,
                          const float* __restrict__ b, float* __restrict__ s_f32,
                          unsigned short* __restrict__ hi, unsigned short* __restrict__ lo){
  int row = blockIdx.x, t = threadIdx.x;
  long base = (long)row * DD + t * 4;
  float4 xv = *(const float4*)(h + base);
  float4 xb = *(const float4*)(hb + base);
  xv.x += xb.x; xv.y += xb.y; xv.z += xb.z; xv.w += xb.w;
  __shared__ float scratch[4];
  float sum = block_sum256(xv.x + xv.y + xv.z + xv.w, scratch);
  float ssq = block_sum256(xv.x*xv.x + xv.y*xv.y + xv.z*xv.z + xv.w*xv.w, scratch);
  float mu = sum * (1.0f / DD);
  float var = ssq * (1.0f / DD) - mu * mu;
  float rstd = rsqrtf(var + 1e-5f);
  float4 wv = *(const float4*)(w + t * 4), bv = *(const float4*)(b + t * 4);
  float y0 = (xv.x - mu) * rstd * wv.x + bv.x;
  float y1 = (xv.y - mu) * rstd * wv.y + bv.y;
  float y2 = (xv.z - mu) * rstd * wv.z + bv.z;
  float y3 = (xv.w - mu) * rstd * wv.w + bv.w;
  float4 o; o.x = y0; o.y = y1; o.z = y2; o.w = y3;
  *(float4*)(s_f32 + base) = o;
  ushort4 hv, lv;
  hv.x = f2bf(y0); lv.x = f2bf(y0 - bf2f(hv.x));
  hv.y = f2bf(y1); lv.y = f2bf(y1 - bf2f(hv.y));
  hv.z = f2bf(y2); lv.z = f2bf(y2 - bf2f(hv.z));
  hv.w = f2bf(y3); lv.w = f2bf(y3 - bf2f(hv.w));
  *(ushort4*)(hi + base) = hv; *(ushort4*)(lo + base) = lv;
}

__global__ void fln_kernel(const float* __restrict__ s, const float* __restrict__ w,
                           const float* __restrict__ b, unsigned short* __restrict__ uhi){
  int row = blockIdx.x, t = threadIdx.x;
  long base = (long)row * DD + t * 4;
  float4 xv = *(const float4*)(s + base);
  __shared__ float scratch[4];
  float sum = block_sum256(xv.x + xv.y + xv.z + xv.w, scratch);
  float ssq = block_sum256(xv.x*xv.x + xv.y*xv.y + xv.z*xv.z + xv.w*xv.w, scratch);
  float mu = sum * (1.0f / DD);
  float var = ssq * (1.0f / DD) - mu * mu;
  float rstd = rsqrtf(var + 1e-5f);
  float4 wv = *(const float4*)(w + t * 4), bv = *(const float4*)(b + t * 4);
  float y0 = (xv.x - mu) * rstd * wv.x + bv.x;
  float y1 = (xv.y - mu) * rstd * wv.y + bv.y;
  float y2 = (xv.z - mu) * rstd * wv.z + bv.z;
  float y3 = (xv.w - mu) * rstd * wv.w + bv.w;
  float n2 = block_sum256(y0*y0 + y1*y1 + y2*y2 + y3*y3, scratch);
  float inv = 1.0f / (sqrtf(n2) + 1e-12f);
  ushort4 o;
  o.x = f2bf(y0 * inv); o.y = f2bf(y1 * inv);
  o.z = f2bf(y2 * inv); o.w = f2bf(y3 * inv);
  *(ushort4*)(uhi + base) = o;
}

// ---------------- loss: combine per-wave sum-exp partials (500 per row) --------------
__global__ void lse_reduce_kernel(const float* __restrict__ psum,
                                  const float* __restrict__ logits, const int* __restrict__ labels,
                                  float* __restrict__ lrow){
  int idx = blockIdx.x;               // 0..4093
  int b = idx / (SS - 1), qq = idx - b * (SS - 1);
  int row = b * SS + qq;
  int t = threadIdx.x;                // 64 threads
  float l = 0.f;
  for (int p = t; p < 500; p += 64) l += psum[((long)row << 9) + p];
  #pragma unroll
  for (int o = 1; o < 64; o <<= 1) l += __shfl_xor(l, o, 64);
  if (t == 0){
    float lse = __logf(l);
    float tl = logits[(long)row * VV + labels[row + 1]];
    lrow[idx] = lse - tl;
  }
}

__global__ void loss_reduce_kernel(const float* __restrict__ lrow, float* __restrict__ dst){
  __shared__ float scratch[4];
  float s = 0.f;
  for (int j = threadIdx.x; j < BB * (SS - 1); j += 256) s += lrow[j];
  float tot = block_sum256(s, scratch);
  if (threadIdx.x == 0) dst[0] = tot / (float)(BB * (SS - 1));
}

// ---------------- launch ------------------------------------------------------------
extern "C" void kernel_launch(void* const* d_in, const int* in_sizes, int n_in,
                              void* d_out, int out_size, void* d_ws, size_t ws_size,
                              hipStream_t stream) {
  const int*   ids    = (const int*)d_in[0];
  const int*   labels = (const int*)d_in[1];
  const float* proj_w = (const float*)d_in[2];
  const float* proj_b = (const float*)d_in[3];
  const float* ln_w   = (const float*)d_in[4];
  const float* ln_b   = (const float*)d_in[5];
  const float* fln_w  = (const float*)d_in[6];
  const float* fln_b  = (const float*)d_in[7];
  const float* out_w  = (const float*)d_in[8];
  float* out = (float*)d_out;

  char* ws = (char*)d_ws;
  float*          s_f32 = (float*)(ws + 0);                    // 16.78 MB
  unsigned short* op_hi = (unsigned short*)(ws + 16777216);    //  8.39 MB
  unsigned short* op_lo = (unsigned short*)(ws + 25165824);    //  8.39 MB
  unsigned short* T_hi  = (unsigned short*)(ws + 33554432);    //  8.39 MB
  unsigned short* T_lo  = (unsigned short*)(ws + 41943040);    //  8.39 MB
  float*          k1    = (float*)(ws + 50331648);             // 16.78 MB
  float*          k2    = (float*)(ws + 67108864);             // 16.78 MB (k1b/hb home)
  unsigned short* sc_hi = (unsigned short*)(ws + 83886080);    //  8.39 MB
  unsigned short* sc_lo = (unsigned short*)(ws + 92274688);    //  8.39 MB
  unsigned short* WhiT  = (unsigned short*)(ws + 100663296);   // 16.78 MB [L][n][k]
  unsigned short* WloT  = (unsigned short*)(ws + 117440512);   // 16.78 MB
  float*          energy= (float*)(ws + 134217728);
  float*          lrow  = (float*)(ws + 134234368);
  unsigned short* owT   = T_hi;  // 65.54 MB overlay (dead zone at vocab time)
  float*          psum  = (float*)(ws + 0);          // overlays s_f32 (dead after fln)
  float*          k1b   = k2;                        // k2 buffer dead during PV1
  float*          k2b   = (float*)(ws + 16777216);   // op region dead during PV2
  float*          hb    = k2;                        // proj ks=1 partial

  // proj_w [L][k][n] -> WhiT/WloT [L][n][k] (fp32-split bf16)
  transpose_f32_bf16_kernel<true><<<dim3(16, 16, 8), 256, 0, stream>>>(proj_w, WhiT, WloT, DD, DD);
  // encode
  encode_kernel<<<NROWS, 256, 0, stream>>>(ids, s_f32, op_hi, op_lo);
  transpose_bf16_pair_kernel<<<dim3(16, 32, 4), 256, 0, stream>>>(op_hi, op_lo, T_hi, T_lo, SS, DD);

  for (int l = 0; l < LL; ++l){
    // score1 = tril(states @ statesT)/32  -> bf16 hi/lo  (128x64 causal tiles, r16)
    score64_kernel<<<dim3(272, 2), 512, 0, stream>>>(op_hi, op_lo, sc_hi, sc_lo, 0.03125f);
    // k1 = score1 @ states  (split-K: ks0 -> k1, ks1 -> k1b)
    gemm_nt_kernel<5, 3><<<dim3(192, 2), 512, 0, stream>>>(
        sc_hi, sc_lo, T_hi, T_lo, k1, (unsigned short*)k1b, nullptr, nullptr,
        SS, SS, SS, DD, 24, 8, (long)SS * SS, (long)DD * SS, (long)SS * DD, 1.0f);
    // combine + mid = s + dt*k1 -> op hi/lo + T hi/lo (transpose fused)
    mid_trans_kernel<<<dim3(16, 64), 256, 0, stream>>>(s_f32, k1, k1b, op_hi, op_lo, T_hi, T_lo);
    // score2 = tril(mid @ midT)/32
    score64_kernel<<<dim3(272, 2), 512, 0, stream>>>(op_hi, op_lo, sc_hi, sc_lo, 0.03125f);
    // k2 = score2 @ mid  (split-K: ks0 -> k2, ks1 -> k2b)
    gemm_nt_kernel<5, 3><<<dim3(192, 2), 512, 0, stream>>>(
        sc_hi, sc_lo, T_hi, T_lo, k2, (unsigned short*)k2b, nullptr, nullptr,
        SS, SS, SS, DD, 24, 8, (long)SS * SS, (long)DD * SS, (long)SS * DD, 1.0f);
    // ev = s + 0.5dt*(k1 + k2a + k2b) (into k2) + row energies
    ev_energy_kernel<<<NROWS, 256, 0, stream>>>(s_f32, k1, k2, k2b, energy);
    // tunneling (batch-mean fused)
    tunnel_kernel<<<NROWS, 256, 0, stream>>>(k2, energy, op_hi, op_lo);
    // h = ev @ proj_w[l] + proj_b[l]  (split-K uniform: ks0+bias -> k1, ks1 -> hb=k2)
    gemm_nt_kernel<0, 4><<<dim3(512, 1), 512, 0, stream>>>(
        op_hi, op_lo, WhiT + (long)l * DD * DD, WloT + (long)l * DD * DD,
        k1, (unsigned short*)hb, nullptr, proj_b + l * DD,
        DD, DD, DD, DD, 32, 8, 0, 0, 0, 1.0f);
    // states = LN(k1 + hb)
    ln_kernel<<<NROWS, 256, 0, stream>>>(k1, hb, ln_w + l * DD, ln_b + l * DD, s_f32, op_hi, op_lo);
    if (l < LL - 1){
      transpose_bf16_pair_kernel<<<dim3(16, 32, 4), 256, 0, stream>>>(op_hi, op_lo, T_hi, T_lo, SS, DD);
    }
  }

  // out_w [k][v] -> owT [v][k] bf16 (plain); u = unit(LN(states)) -> op_hi
  transpose_f32_bf16_kernel<false><<<dim3(500, 16, 1), 256, 0, stream>>>(out_w, owT, nullptr, DD, VV);
  fln_kernel<<<NROWS, 256, 0, stream>>>(s_f32, fln_w, fln_b, op_hi);
  // logits = u @ out_w  (128^2, 2 blocks/CU) + fused max-free sum-exp partials
  gemm256_kernel<<<8000, 512, 0, stream>>>(op_hi, owT, out, psum);
  // loss from partials
  lse_reduce_kernel<<<BB * (SS - 1), 64, 0, stream>>>(psum, out, labels, lrow);
  loss_reduce_kernel<<<1, 256, 0, stream>>>(lrow, out + (long)NROWS * VV);
}